// Round 11
// baseline (389.771 us; speedup 1.0000x reference)
//
#include <hip/hip_runtime.h>
#include <hip/hip_bf16.h>
#include <math.h>

#define B_ 16
#define T_ 512
#define H_ 768
#define S_ 32
#define L_ 50
#define NT_ 3
#define HS_ 3072
#define CH_ 32
#define CT_ 16  // T_/CH_

// Row compaction: starts in [1,400), L=50  =>  pc <= 448, pre-index <= 449.
// TX_=464 rows/batch (29*16 chunks); regions 256-aligned so every 256-row
// GEMM m-tile uses a single W-panel.
#define TX_ 464
#define YB2 7424
#define GB 14848
#define CLSB 15360
#define XYROWS 14848
#define AROWS 15616        // = 61 * 256 exactly
#define NKT 24             // 768 / BK32
#define SLOT_SH 16384      // shorts per LDS slot: A 8192 + B 8192 (32 KiB)
#define P1_BLOCKS (B_ * CH_ * 192 / 256)   // 384

typedef __attribute__((ext_vector_type(8))) short short8;
typedef __attribute__((ext_vector_type(4))) float f32x4;

__device__ __forceinline__ unsigned short f2bf(float f) {
    __hip_bfloat16 b = __float2bfloat16(f);
    return *(unsigned short*)&b;
}
__device__ __forceinline__ float bf2f(unsigned short u) {
    union { unsigned int i; float f; } v; v.i = ((unsigned int)u) << 16; return v.f;
}
__device__ __forceinline__ void load_lds16(const void* g, void* l) {
    __builtin_amdgcn_global_load_lds((__attribute__((address_space(1))) void*)g,
                                     (__attribute__((address_space(3))) void*)l, 16, 0, 0);
}
__device__ __forceinline__ ushort4 pack4(float4 v) {
    ushort4 o; o.x = f2bf(v.x); o.y = f2bf(v.y); o.z = f2bf(v.z); o.w = f2bf(v.w);
    return o;
}

// branch-free exact-gelu: Abramowitz-Stegun 3-term erf, max err 2.5e-5
__device__ __forceinline__ float gelu_exact(float v) {
    float a = fabsf(v) * 0.70710678118654752f;
    float t = __builtin_amdgcn_rcpf(fmaf(a, 0.47047f, 1.0f));
    float poly = t * fmaf(t, fmaf(t, 0.7478556f, -0.0958798f), 0.3480242f);
    float e = __builtin_amdgcn_exp2f(a * a * -1.4426950408889634f);
    float erfa = fmaf(-poly, e, 1.0f);
    float erfv = copysignf(erfa, v);
    return 0.5f * v * (1.0f + erfv);
}

// ---------------------------------------------------------------------------
// prep: fused {cumsum pass1 partials | W1 transpose | ctr zero}. Disjoint
// block ranges; saves one dispatch (~10-15 us launch+drain on this harness).
// ---------------------------------------------------------------------------
__global__ __launch_bounds__(256) void prep_kernel(const float4* __restrict__ h4,
                                                   float4* __restrict__ partial,
                                                   const float* __restrict__ W1,
                                                   __hip_bfloat16* __restrict__ Wt,
                                                   int* __restrict__ ctr) {
    __shared__ float tile[64][65];
    if (blockIdx.x < P1_BLOCKS) {
        if (blockIdx.x == 0 && threadIdx.x == 0) *ctr = 0;   // reset for combine
        int idx = blockIdx.x * 256 + threadIdx.x;            // (b, ch, hd4)
        int hd4 = idx % 192; int t = idx / 192; int ch = t % CH_; int b = t / CH_;
        const float4* hp = h4 + ((size_t)b * T_ + ch * CT_) * 192 + hd4;
        float4 acc = {0.f, 0.f, 0.f, 0.f};
#pragma unroll
        for (int tt = 0; tt < CT_; tt++) {
            float4 v = hp[(size_t)tt * 192];
            acc.x += v.x; acc.y += v.y; acc.z += v.z; acc.w += v.w;
        }
        partial[idx] = acc;
        return;
    }
    int bx = blockIdx.x - P1_BLOCKS;
    int n0 = (bx % 48) * 64, k0 = (bx / 48) * 64;
    int c = threadIdx.x & 63, r0 = threadIdx.x >> 6;
#pragma unroll
    for (int i = 0; i < 16; i++) {
        int r = r0 + i * 4;
        tile[r][c] = W1[(size_t)(k0 + r) * HS_ + n0 + c];
    }
    __syncthreads();
    int p = k0 / H_, kl = k0 % H_;
    __hip_bfloat16* out = Wt + (size_t)p * HS_ * H_;
#pragma unroll
    for (int i = 0; i < 16; i++) {
        int r = r0 + i * 4;
        out[(size_t)(n0 + r) * H_ + kl + c] = __float2bfloat16(tile[c][r]);
    }
}

// pass3 (chunk prefix folded in): emit bf16 h + bf16 cumsum into compacted A.
// Blocks >= 384 run the gather path (span-start rows + cls rows) — fused.
__global__ __launch_bounds__(256) void cumsum_pass3(const float4* __restrict__ h4,
                                                    const float4* __restrict__ partial,
                                                    ushort4* __restrict__ Ab4,
                                                    const float* __restrict__ h,
                                                    const int* __restrict__ starts) {
    if (blockIdx.x >= P1_BLOCKS) {
        // gather path: 528 blocks
        int r = blockIdx.x - P1_BLOCKS;
        int src_row, dst_row;
        if (r < B_ * S_) {
            int b = r / S_;
            int sv = starts[r];
            int sc = min(max(sv, 0), T_ - 1);
            src_row = b * T_ + sc;
            dst_row = GB + r;
        } else {
            int b = r - B_ * S_;
            src_row = b * T_;
            dst_row = CLSB + b;
        }
        __hip_bfloat16* dst = (__hip_bfloat16*)Ab4 + (size_t)dst_row * H_;
        const float* src = h + (size_t)src_row * H_;
        for (int j = threadIdx.x; j < H_; j += 256)
            dst[j] = __float2bfloat16(src[j]);
        return;
    }
    int idx = blockIdx.x * 256 + threadIdx.x;        // (b, ch, hd4)
    int hd4 = idx % 192; int t = idx / 192; int ch = t % CH_; int b = t / CH_;
    if (ch * CT_ >= TX_) return;                     // dead chunk
    float4 acc = {0.f, 0.f, 0.f, 0.f};
#pragma unroll
    for (int c = 0; c < CH_; c++) {
        if (c < ch) {
            float4 v = partial[((size_t)b * CH_ + c) * 192 + hd4];
            acc.x += v.x; acc.y += v.y; acc.z += v.z; acc.w += v.w;
        }
    }
    const float4* hp = h4 + ((size_t)b * T_ + ch * CT_) * 192 + hd4;
    if (ch == 0) {
        ushort4 z = {0, 0, 0, 0};
        Ab4[((size_t)(YB2 + b * TX_)) * 192 + hd4] = z;   // pre[b][0] = 0
    }
#pragma unroll
    for (int tt = 0; tt < CT_; tt++) {
        int t2 = ch * CT_ + tt;
        float4 hv = hp[(size_t)tt * 192];
        if (t2 < TX_)
            Ab4[((size_t)(b * TX_ + t2)) * 192 + hd4] = pack4(hv);
        acc.x += hv.x; acc.y += hv.y; acc.z += hv.z; acc.w += hv.w;
        if (t2 + 1 < TX_)
            Ab4[((size_t)(YB2 + b * TX_ + t2 + 1)) * 192 + hd4] = pack4(acc);
    }
}

// ---------------------------------------------------------------------------
// mega MFMA GEMM — round-2 pinned config (100 us, FETCH 76 MB, 0 bank
// conflicts): 256x256 tile, 8 waves (2Mx4N), 16x16x32 bf16, BK=32,
// 4-slot LDS ring, XOR chunk swizzle (p ^ ((row>>1)&3)) applied on both
// sides, counted vmcnt(8), 2 phases/tile. Rounds 1/3/4 A/B'd coarse-ring,
// m201 phase order, and 128²@3-blocks/CU — all equal or worse.
// ---------------------------------------------------------------------------
__device__ __forceinline__ void mfma16(const short8 (&a)[4], const short8 (&b)[4],
                                       f32x4 (&acc)[8][4], int off) {
#pragma unroll
    for (int mf = 0; mf < 4; ++mf)
#pragma unroll
        for (int nf = 0; nf < 4; ++nf)
            acc[off + mf][nf] = __builtin_amdgcn_mfma_f32_16x16x32_bf16(
                a[mf], b[nf], acc[off + mf][nf], 0, 0, 0);
}

#define STAGE_A(nslot, k0_) {                                                  \
    char* d_ = (char*)(nslot) + dstoff;                                        \
    load_lds16(pA + (k0_), d_);                                                \
    load_lds16(pA + (size_t)128 * H_ + (k0_), d_ + 8192);                      \
}
#define STAGE_B(nslot, k0_) {                                                  \
    char* d_ = (char*)(nslot) + 16384 + dstoff;                                \
    load_lds16(pB + (k0_), d_);                                                \
    load_lds16(pB + (size_t)128 * H_ + (k0_), d_ + 8192);                      \
}

#define TILE_STEP(kt, WAITSTR, DO_STAGE)                                       \
  {                                                                            \
    const short* slot = lds + ((kt) & 3) * SLOT_SH;                            \
    short* nslot = lds + (((kt) + 3) & 3) * SLOT_SH;                           \
    asm volatile(WAITSTR ::: "memory");                                        \
    __builtin_amdgcn_s_barrier();                                              \
    __builtin_amdgcn_sched_barrier(0);                                         \
    short8 a[4], b[4];                                                         \
    _Pragma("unroll")                                                          \
    for (int i = 0; i < 4; ++i)                                                \
      a[i] = *(const short8*)&slot[(wr * 128 + i * 16 + l15) * 32 + pcs];      \
    _Pragma("unroll")                                                          \
    for (int i = 0; i < 4; ++i)                                                \
      b[i] = *(const short8*)&slot[8192 + (wc * 64 + i * 16 + l15) * 32 + pcs];\
    if (DO_STAGE) { STAGE_A(nslot, ((kt) + 3) * 32) }                          \
    asm volatile("s_waitcnt lgkmcnt(0)" ::: "memory");                         \
    __builtin_amdgcn_sched_barrier(0);                                         \
    __builtin_amdgcn_s_setprio(1);                                             \
    mfma16(a, b, acc, 0);                                                      \
    __builtin_amdgcn_s_setprio(0);                                             \
    __builtin_amdgcn_s_barrier();                                              \
    _Pragma("unroll")                                                          \
    for (int i = 0; i < 4; ++i)                                                \
      a[i] = *(const short8*)&slot[(wr * 128 + 64 + i * 16 + l15) * 32 + pcs]; \
    if (DO_STAGE) { STAGE_B(nslot, ((kt) + 3) * 32) }                          \
    asm volatile("s_waitcnt lgkmcnt(0)" ::: "memory");                         \
    __builtin_amdgcn_sched_barrier(0);                                         \
    __builtin_amdgcn_s_setprio(1);                                             \
    mfma16(a, b, acc, 4);                                                      \
    __builtin_amdgcn_s_setprio(0);                                             \
  }

__global__ __launch_bounds__(512, 2) void mfma_gemm(const __hip_bfloat16* __restrict__ Ab,
                                                    const __hip_bfloat16* __restrict__ Wt,
                                                    __hip_bfloat16* __restrict__ XY,
                                                    float* __restrict__ ST,
                                                    float* __restrict__ CC) {
    __shared__ short lds[4 * SLOT_SH];   // 128 KiB
    int tid = threadIdx.x;
    int wave = tid >> 6, lane = tid & 63;
    int wr = wave >> 2, wc = wave & 3;
    int l15 = lane & 15;
    int pcs = ((lane >> 4) ^ ((l15 >> 1) & 3)) * 8;   // swizzled chunk, in shorts

    // bijective XCD swizzle: nwg=732, q=91, r=4 (m204 formula)
    int orig = blockIdx.x;
    int xcd = orig & 7, loc = orig >> 3;
    int wg = (xcd < 4 ? xcd * 92 : 368 + (xcd - 4) * 91) + loc;
    int mt = wg / 12, nt = wg - mt * 12;
    int m0 = mt << 8, n0 = nt << 8;

    const __hip_bfloat16* Bt;
    if (m0 < YB2)        Bt = Wt + (size_t)1 * HS_ * H_;  // X: h_end panel
    else if (m0 < GB)    Bt = Wt + (size_t)2 * HS_ * H_;  // Y: h_mean panel
    else if (m0 < CLSB)  Bt = Wt;                         // ST: h_start panel
    else                 Bt = Wt + (size_t)3 * HS_ * H_;  // CC: cls panel

    // staging addresses: wave w covers rows [w*16, w*16+16) and +128;
    // per-lane logical chunk lc = (lane&3) ^ ((row>>1)&3) = (lane&3)^((lane>>3)&3)
    int srow = wave * 16 + (lane >> 2);
    int lcS = ((lane & 3) ^ ((lane >> 3) & 3)) * 8;       // elements
    const __hip_bfloat16* pA = Ab + (size_t)(m0 + srow) * H_ + lcS;
    const __hip_bfloat16* pB = Bt + (size_t)(n0 + srow) * H_ + lcS;
    int dstoff = wave * 1024;                             // bytes within slot half

    f32x4 acc[8][4] = {};

    // prologue: stage tiles 0,1,2
#pragma unroll
    for (int t = 0; t < 3; ++t) {
        STAGE_A(lds + t * SLOT_SH, t * 32)
        STAGE_B(lds + t * SLOT_SH, t * 32)
    }

    for (int kt = 0; kt < NKT - 3; ++kt)
        TILE_STEP(kt, "s_waitcnt vmcnt(8)", true)
    TILE_STEP(NKT - 3, "s_waitcnt vmcnt(8)", false)
    TILE_STEP(NKT - 2, "s_waitcnt vmcnt(4)", false)
    TILE_STEP(NKT - 1, "s_waitcnt vmcnt(0)", false)

    // C-write. 16x16x32 C/D layout: col(n)=lane&15, row(m)=(lane>>4)*4+reg
    int mb = m0 + wr * 128, nb = n0 + wc * 64;
#pragma unroll
    for (int mf = 0; mf < 8; ++mf) {
#pragma unroll
        for (int nf = 0; nf < 4; ++nf) {
            int n = nb + nf * 16 + l15;
            int mr = mb + mf * 16 + (lane >> 4) * 4;
#pragma unroll
            for (int r = 0; r < 4; ++r) {
                int m = mr + r;
                float v = acc[mf][nf][r];
                if (m < XYROWS) {
                    XY[(size_t)m * HS_ + n] = __float2bfloat16(v);
                } else if (m < CLSB) {
                    ST[(size_t)(m - GB) * HS_ + n] = v;
                } else if (m < CLSB + 16) {
                    CC[(size_t)(m - CLSB) * HS_ + n] = v;
                }
            }
        }
    }
}

// ---------------------------------------------------------------------------
// combine — r10-proven body (LDS-staged per-span streams, one 512-thread
// block per (b,s), 2 blocks/CU), with loss_kernel FOLDED IN via the
// last-block-done pattern: each block releases its scores/tgold with
// __threadfence (device scope, G16-sanctioned), bumps a counter; the block
// observing B_*S_-1 re-fences and runs the 512-thread loss reduction.
// No dispatch-order assumption; ctr re-zeroed each replay by prep_kernel.
// Saves the 1-block loss dispatch (full launch+drain for ~5 us of work).
// ---------------------------------------------------------------------------
__global__ __launch_bounds__(512, 4) void combine_kernel(
    const float* __restrict__ ST, const float* __restrict__ CC,
    const float* __restrict__ b1, const float* __restrict__ w_score,
    const __hip_bfloat16* __restrict__ XY,
    const float* __restrict__ b_score, const float* __restrict__ W_type,
    const int* __restrict__ starts, const int* __restrict__ ends,
    const int* __restrict__ mask, const int* __restrict__ types,
    const float* __restrict__ b_type,
    float* __restrict__ scores, float* __restrict__ tgold,
    int* __restrict__ ctr, float* __restrict__ out) {
    __shared__ unsigned short ysL[HS_];
    __shared__ unsigned short cvL[HS_];
    __shared__ unsigned short wvL[HS_];
    int x = blockIdx.x;
    int b = x & 15, s = x >> 4;          // XCD = x%8 = b%8
    int bs = b * S_ + s;
    int tid = threadIdx.x;
    int wave = tid >> 6, lane = tid & 63;
    int sv = starts[bs], ev = ends[bs];
    int gi = min(max(ev - sv, 0), L_ - 1);
    int sc = min(max(sv, 0), TX_ - 1);
    float bs0 = b_score[0];

    // stage shared streams into LDS (once per block)
    const unsigned short* Ysr = (const unsigned short*)(XY + (size_t)(YB2 + b * TX_ + sc) * HS_);
    const float* STr = ST + (size_t)bs * HS_;
    const float* CCr = CC + (size_t)b * HS_;
    union U8 { short8 s; unsigned short u[8]; };
    for (int d = tid * 8; d < HS_; d += 512 * 8) {
        *(short8*)&ysL[d] = *(const short8*)(Ysr + d);
        float4 sa = *(const float4*)(STr + d), sb = *(const float4*)(STr + d + 4);
        float4 ca = *(const float4*)(CCr + d), cb = *(const float4*)(CCr + d + 4);
        float4 ba = *(const float4*)(b1 + d),  bb = *(const float4*)(b1 + d + 4);
        U8 uc;
        uc.u[0] = f2bf(sa.x + ca.x + ba.x); uc.u[1] = f2bf(sa.y + ca.y + ba.y);
        uc.u[2] = f2bf(sa.z + ca.z + ba.z); uc.u[3] = f2bf(sa.w + ca.w + ba.w);
        uc.u[4] = f2bf(sb.x + cb.x + bb.x); uc.u[5] = f2bf(sb.y + cb.y + bb.y);
        uc.u[6] = f2bf(sb.z + cb.z + bb.z); uc.u[7] = f2bf(sb.w + cb.w + bb.w);
        *(short8*)&cvL[d] = uc.s;
        float4 wa = *(const float4*)(w_score + d), wb = *(const float4*)(w_score + d + 4);
        U8 uw;
        uw.u[0] = f2bf(wa.x); uw.u[1] = f2bf(wa.y); uw.u[2] = f2bf(wa.z); uw.u[3] = f2bf(wa.w);
        uw.u[4] = f2bf(wb.x); uw.u[5] = f2bf(wb.y); uw.u[6] = f2bf(wb.z); uw.u[7] = f2bf(wb.w);
        *(short8*)&wvL[d] = uw.s;
    }
    __syncthreads();

    for (int pr = wave; pr < L_ / 2; pr += 8) {
        int l0 = pr * 2, l1 = l0 + 1;
        int pc0 = min(max(sv + l0, 0), TX_ - 2);
        int pc1 = min(max(sv + l1, 0), TX_ - 2);
        float inv0 = 1.0f / (float)(l0 + 1);
        float inv1 = 1.0f / (float)(l1 + 1);
        bool isg0 = (l0 == gi), isg1 = (l1 == gi);
        bool anyg = isg0 || isg1;

        const unsigned short* X0 = (const unsigned short*)(XY + (size_t)(b * TX_ + pc0) * HS_);
        const unsigned short* X1 = (const unsigned short*)(XY + (size_t)(b * TX_ + pc1) * HS_);
        const unsigned short* Y0 = (const unsigned short*)(XY + (size_t)(YB2 + b * TX_ + pc0 + 1) * HS_);
        const unsigned short* Y1 = (const unsigned short*)(XY + (size_t)(YB2 + b * TX_ + pc1 + 1) * HS_);

        float local0 = 0.f, local1 = 0.f, t0 = 0.f, t1 = 0.f, t2 = 0.f;
#pragma unroll 2
        for (int j = 0; j < 6; j++) {
            int d = j * 512 + lane * 8;
            short8 xv0 = *(const short8*)(X0 + d);
            short8 xv1 = *(const short8*)(X1 + d);
            short8 yv0 = *(const short8*)(Y0 + d);
            short8 yv1 = *(const short8*)(Y1 + d);
            short8 ys8 = *(const short8*)&ysL[d];
            short8 cv8 = *(const short8*)&cvL[d];
            short8 wv8 = *(const short8*)&wvL[d];
#pragma unroll
            for (int q = 0; q < 8; q++) {
                float ys = bf2f(((const unsigned short*)&ys8)[q]);
                float cvq = bf2f(((const unsigned short*)&cv8)[q]);
                float w  = bf2f(((const unsigned short*)&wv8)[q]);
                float v0 = fmaf(bf2f(((const unsigned short*)&yv0)[q]) - ys, inv0, cvq) +
                           bf2f(((const unsigned short*)&xv0)[q]);
                float v1 = fmaf(bf2f(((const unsigned short*)&yv1)[q]) - ys, inv1, cvq) +
                           bf2f(((const unsigned short*)&xv1)[q]);
                float g0 = gelu_exact(v0);
                float g1 = gelu_exact(v1);
                local0 = fmaf(g0, w, local0);
                local1 = fmaf(g1, w, local1);
                if (anyg) {   // wave-uniform branch
                    float gg = isg0 ? g0 : g1;
                    t0 = fmaf(gg, W_type[(d + q) * NT_ + 0], t0);
                    t1 = fmaf(gg, W_type[(d + q) * NT_ + 1], t1);
                    t2 = fmaf(gg, W_type[(d + q) * NT_ + 2], t2);
                }
            }
        }
#pragma unroll
        for (int off = 32; off >= 1; off >>= 1) {
            local0 += __shfl_down(local0, off);
            local1 += __shfl_down(local1, off);
        }
        if (lane == 0) {
            scores[(size_t)bs * L_ + l0] = local0 + bs0;
            scores[(size_t)bs * L_ + l1] = local1 + bs0;
        }
        if (anyg) {
#pragma unroll
            for (int off = 32; off >= 1; off >>= 1) {
                t0 += __shfl_down(t0, off);
                t1 += __shfl_down(t1, off);
                t2 += __shfl_down(t2, off);
            }
            if (lane == 0) {
                tgold[bs * NT_ + 0] = t0;
                tgold[bs * NT_ + 1] = t1;
                tgold[bs * NT_ + 2] = t2;
            }
        }
    }

    // ---- fused loss: last block to finish runs the final reduction ----
    __syncthreads();                 // all waves' stores issued & drained
    __threadfence();                 // device-scope release (L2 writeback)
    __shared__ int amLast;
    if (tid == 0) amLast = (atomicAdd(ctr, 1) == B_ * S_ - 1) ? 1 : 0;
    __syncthreads();
    if (!amLast) return;
    __threadfence();                 // acquire: see all blocks' scores/tgold
    {
        __shared__ int svl[B_];
        __shared__ float r[3][8];
        int lb = tid / S_;
        if (tid < B_) svl[tid] = 0;
        __syncthreads();
        {
            int part = 0;
            const int* mp = mask + tid * 16;
#pragma unroll
            for (int i = 0; i < 16; i++) part += mp[i];
            atomicAdd(&svl[tid / (T_ / 16)], part);
        }
        __syncthreads();
        int vl = svl[lb];
        int lt = max(1, vl - 2);
        int sv2 = starts[tid], ev2 = ends[tid];
        int gold = ev2 - sv2;
        bool valid = (sv2 >= 1) && (sv2 <= lt) && (ev2 >= sv2) && (ev2 <= lt) && (gold < L_);
        int emax = min(sv2 + L_ - 1, lt);
        const float* sp = scores + (size_t)tid * L_;
        float m = -1e30f;
        for (int l = 0; l < L_; l++) {
            float v = (sv2 + l <= emax) ? sp[l] : -1e9f;
            m = fmaxf(m, v);
        }
        float sum = 0.f;
        for (int l = 0; l < L_; l++) {
            float v = (sv2 + l <= emax) ? sp[l] : -1e9f;
            sum += expf(v - m);
        }
        int gi2 = min(max(gold, 0), L_ - 1);
        float vg = (sv2 + gi2 <= emax) ? sp[gi2] : -1e9f;
        float end_loss = (m + logf(sum)) - vg;

        float u0 = tgold[tid * 3 + 0] + b_type[0];
        float u1 = tgold[tid * 3 + 1] + b_type[1];
        float u2 = tgold[tid * 3 + 2] + b_type[2];
        float tm = fmaxf(u0, fmaxf(u1, u2));
        float tsum = expf(u0 - tm) + expf(u1 - tm) + expf(u2 - tm);
        int tg = min(max(types[tid], 0), NT_ - 1);
        float tv = (tg == 0) ? u0 : ((tg == 1) ? u1 : u2);
        float type_loss = (tm + logf(tsum)) - tv;

        float ve = valid ? end_loss : 0.f;
        float vt = valid ? type_loss : 0.f;
        float vc = valid ? 1.f : 0.f;
        for (int off = 32; off >= 1; off >>= 1) {
            ve += __shfl_down(ve, off);
            vt += __shfl_down(vt, off);
            vc += __shfl_down(vc, off);
        }
        if ((tid & 63) == 0) {
            int w = tid >> 6;
            r[0][w] = ve; r[1][w] = vt; r[2][w] = vc;
        }
        __syncthreads();
        if (tid == 0) {
            float se = 0, st = 0, n = 0;
            for (int w = 0; w < 8; w++) { se += r[0][w]; st += r[1][w]; n += r[2][w]; }
            float denom = fmaxf(n, 1.f);
            out[0] = (n > 0.f) ? (se / denom + st / denom) : 0.f;
        }
    }
}

// ---------------------------------------------------------------------------
extern "C" void kernel_launch(void* const* d_in, const int* in_sizes, int n_in,
                              void* d_out, int out_size, void* d_ws, size_t ws_size,
                              hipStream_t stream) {
    const float* h       = (const float*)d_in[0];
    const int*   mask    = (const int*)d_in[1];
    const int*   starts  = (const int*)d_in[2];
    const int*   ends    = (const int*)d_in[3];
    const int*   types   = (const int*)d_in[4];
    const float* W1      = (const float*)d_in[5];
    const float* b1      = (const float*)d_in[6];
    const float* w_score = (const float*)d_in[7];
    const float* b_score = (const float*)d_in[8];
    const float* W_type  = (const float*)d_in[9];
    const float* b_type  = (const float*)d_in[10];
    float* out = (float*)d_out;

    char* ws = (char*)d_ws;
    size_t off = 0;
    __hip_bfloat16* Ab = (__hip_bfloat16*)(ws + off); off += (size_t)AROWS * H_ * 2;
    __hip_bfloat16* XY = (__hip_bfloat16*)(ws + off); off += (size_t)XYROWS * HS_ * 2;
    __hip_bfloat16* Wt = (__hip_bfloat16*)(ws + off); off += (size_t)4 * HS_ * H_ * 2;
    float* ST     = (float*)(ws + off);               off += (size_t)512 * HS_ * 4;
    float* CC     = (float*)(ws + off);               off += (size_t)16 * HS_ * 4;
    float* scores = (float*)(ws + off);               off += (size_t)B_ * S_ * L_ * 4;
    float* tgold  = (float*)(ws + off);               off += (size_t)B_ * S_ * NT_ * 4;
    int*   ctr    = (int*)(ws + off);                 off += 64;
    float4* partial = (float4*)XY;  // aliases XY; consumed by pass3 before GEMM writes XY

    hipLaunchKernelGGL(prep_kernel, dim3(P1_BLOCKS + 48 * 48), dim3(256), 0, stream,
                       (const float4*)h, partial, W1, Wt, ctr);
    hipLaunchKernelGGL(cumsum_pass3, dim3(P1_BLOCKS + B_ * S_ + B_), dim3(256),
                       0, stream, (const float4*)h, (const float4*)partial, (ushort4*)Ab,
                       h, starts);
    hipLaunchKernelGGL(mfma_gemm, dim3((AROWS / 256) * 12), dim3(512), 0, stream,
                       Ab, Wt, XY, ST, CC);
    hipLaunchKernelGGL(combine_kernel, dim3(B_ * S_), dim3(512), 0, stream,
                       ST, CC, b1, w_score, XY, b_score, W_type, starts, ends,
                       mask, types, b_type, scores, tgold, ctr, out);
}

// Round 12
// 304.555 us; speedup vs baseline: 1.2798x; 1.2798x over previous
//
#include <hip/hip_runtime.h>
#include <hip/hip_bf16.h>
#include <math.h>

#define B_ 16
#define T_ 512
#define H_ 768
#define S_ 32
#define L_ 50
#define NT_ 3
#define HS_ 3072
#define CH_ 32
#define CT_ 16  // T_/CH_

// Row compaction: starts in [1,400), L=50  =>  pc <= 448, pre-index <= 449.
// TX_=464 rows/batch (29*16 chunks); regions 256-aligned so every 256-row
// GEMM m-tile uses a single W-panel.
#define TX_ 464
#define YB2 7424
#define GB 14848
#define CLSB 15360
#define XYROWS 14848
#define AROWS 15616        // = 61 * 256 exactly
#define NKT 24             // 768 / BK32
#define SLOT_SH 16384      // shorts per LDS slot: A 8192 + B 8192 (32 KiB)
#define P1_BLOCKS (B_ * CH_ * 192 / 256)   // 384

typedef __attribute__((ext_vector_type(8))) short short8;
typedef __attribute__((ext_vector_type(4))) float f32x4;

__device__ __forceinline__ unsigned short f2bf(float f) {
    __hip_bfloat16 b = __float2bfloat16(f);
    return *(unsigned short*)&b;
}
__device__ __forceinline__ float bf2f(unsigned short u) {
    union { unsigned int i; float f; } v; v.i = ((unsigned int)u) << 16; return v.f;
}
__device__ __forceinline__ void load_lds16(const void* g, void* l) {
    __builtin_amdgcn_global_load_lds((__attribute__((address_space(1))) void*)g,
                                     (__attribute__((address_space(3))) void*)l, 16, 0, 0);
}
__device__ __forceinline__ ushort4 pack4(float4 v) {
    ushort4 o; o.x = f2bf(v.x); o.y = f2bf(v.y); o.z = f2bf(v.z); o.w = f2bf(v.w);
    return o;
}

// branch-free exact-gelu: Abramowitz-Stegun 3-term erf, max err 2.5e-5
__device__ __forceinline__ float gelu_exact(float v) {
    float a = fabsf(v) * 0.70710678118654752f;
    float t = __builtin_amdgcn_rcpf(fmaf(a, 0.47047f, 1.0f));
    float poly = t * fmaf(t, fmaf(t, 0.7478556f, -0.0958798f), 0.3480242f);
    float e = __builtin_amdgcn_exp2f(a * a * -1.4426950408889634f);
    float erfa = fmaf(-poly, e, 1.0f);
    float erfv = copysignf(erfa, v);
    return 0.5f * v * (1.0f + erfv);
}

// ---------------------------------------------------------------------------
// prep: fused {cumsum pass1 partials | W1 transpose}. Disjoint block ranges;
// saves one dispatch. (r11 A/B: this fusion is benign; the loss-fold's
// __threadfence was the regression — device-scope fences writeback/invalidate
// per-XCD L2 and destroyed combine's cache reuse, +76 us. Reverted.)
// ---------------------------------------------------------------------------
__global__ __launch_bounds__(256) void prep_kernel(const float4* __restrict__ h4,
                                                   float4* __restrict__ partial,
                                                   const float* __restrict__ W1,
                                                   __hip_bfloat16* __restrict__ Wt) {
    __shared__ float tile[64][65];
    if (blockIdx.x < P1_BLOCKS) {
        int idx = blockIdx.x * 256 + threadIdx.x;            // (b, ch, hd4)
        int hd4 = idx % 192; int t = idx / 192; int ch = t % CH_; int b = t / CH_;
        const float4* hp = h4 + ((size_t)b * T_ + ch * CT_) * 192 + hd4;
        float4 acc = {0.f, 0.f, 0.f, 0.f};
#pragma unroll
        for (int tt = 0; tt < CT_; tt++) {
            float4 v = hp[(size_t)tt * 192];
            acc.x += v.x; acc.y += v.y; acc.z += v.z; acc.w += v.w;
        }
        partial[idx] = acc;
        return;
    }
    int bx = blockIdx.x - P1_BLOCKS;
    int n0 = (bx % 48) * 64, k0 = (bx / 48) * 64;
    int c = threadIdx.x & 63, r0 = threadIdx.x >> 6;
#pragma unroll
    for (int i = 0; i < 16; i++) {
        int r = r0 + i * 4;
        tile[r][c] = W1[(size_t)(k0 + r) * HS_ + n0 + c];
    }
    __syncthreads();
    int p = k0 / H_, kl = k0 % H_;
    __hip_bfloat16* out = Wt + (size_t)p * HS_ * H_;
#pragma unroll
    for (int i = 0; i < 16; i++) {
        int r = r0 + i * 4;
        out[(size_t)(n0 + r) * H_ + kl + c] = __float2bfloat16(tile[c][r]);
    }
}

// pass3 (chunk prefix folded in): emit bf16 h + bf16 cumsum into compacted A.
// Blocks >= 384 run the gather path (span-start rows + cls rows) — fused.
__global__ __launch_bounds__(256) void cumsum_pass3(const float4* __restrict__ h4,
                                                    const float4* __restrict__ partial,
                                                    ushort4* __restrict__ Ab4,
                                                    const float* __restrict__ h,
                                                    const int* __restrict__ starts) {
    if (blockIdx.x >= P1_BLOCKS) {
        // gather path: 528 blocks
        int r = blockIdx.x - P1_BLOCKS;
        int src_row, dst_row;
        if (r < B_ * S_) {
            int b = r / S_;
            int sv = starts[r];
            int sc = min(max(sv, 0), T_ - 1);
            src_row = b * T_ + sc;
            dst_row = GB + r;
        } else {
            int b = r - B_ * S_;
            src_row = b * T_;
            dst_row = CLSB + b;
        }
        __hip_bfloat16* dst = (__hip_bfloat16*)Ab4 + (size_t)dst_row * H_;
        const float* src = h + (size_t)src_row * H_;
        for (int j = threadIdx.x; j < H_; j += 256)
            dst[j] = __float2bfloat16(src[j]);
        return;
    }
    int idx = blockIdx.x * 256 + threadIdx.x;        // (b, ch, hd4)
    int hd4 = idx % 192; int t = idx / 192; int ch = t % CH_; int b = t / CH_;
    if (ch * CT_ >= TX_) return;                     // dead chunk
    float4 acc = {0.f, 0.f, 0.f, 0.f};
#pragma unroll
    for (int c = 0; c < CH_; c++) {
        if (c < ch) {
            float4 v = partial[((size_t)b * CH_ + c) * 192 + hd4];
            acc.x += v.x; acc.y += v.y; acc.z += v.z; acc.w += v.w;
        }
    }
    const float4* hp = h4 + ((size_t)b * T_ + ch * CT_) * 192 + hd4;
    if (ch == 0) {
        ushort4 z = {0, 0, 0, 0};
        Ab4[((size_t)(YB2 + b * TX_)) * 192 + hd4] = z;   // pre[b][0] = 0
    }
#pragma unroll
    for (int tt = 0; tt < CT_; tt++) {
        int t2 = ch * CT_ + tt;
        float4 hv = hp[(size_t)tt * 192];
        if (t2 < TX_)
            Ab4[((size_t)(b * TX_ + t2)) * 192 + hd4] = pack4(hv);
        acc.x += hv.x; acc.y += hv.y; acc.z += hv.z; acc.w += hv.w;
        if (t2 + 1 < TX_)
            Ab4[((size_t)(YB2 + b * TX_ + t2 + 1)) * 192 + hd4] = pack4(acc);
    }
}

// ---------------------------------------------------------------------------
// mega MFMA GEMM — round-2 pinned config (100 us, FETCH 76 MB, 0 bank
// conflicts): 256x256 tile, 8 waves (2Mx4N), 16x16x32 bf16, BK=32,
// 4-slot LDS ring, XOR chunk swizzle (p ^ ((row>>1)&3)) applied on both
// sides, counted vmcnt(8), 2 phases/tile. Rounds 1/3/4 A/B'd coarse-ring,
// m201 phase order, and 128²@3-blocks/CU — all equal or worse.
// ---------------------------------------------------------------------------
__device__ __forceinline__ void mfma16(const short8 (&a)[4], const short8 (&b)[4],
                                       f32x4 (&acc)[8][4], int off) {
#pragma unroll
    for (int mf = 0; mf < 4; ++mf)
#pragma unroll
        for (int nf = 0; nf < 4; ++nf)
            acc[off + mf][nf] = __builtin_amdgcn_mfma_f32_16x16x32_bf16(
                a[mf], b[nf], acc[off + mf][nf], 0, 0, 0);
}

#define STAGE_A(nslot, k0_) {                                                  \
    char* d_ = (char*)(nslot) + dstoff;                                        \
    load_lds16(pA + (k0_), d_);                                                \
    load_lds16(pA + (size_t)128 * H_ + (k0_), d_ + 8192);                      \
}
#define STAGE_B(nslot, k0_) {                                                  \
    char* d_ = (char*)(nslot) + 16384 + dstoff;                                \
    load_lds16(pB + (k0_), d_);                                                \
    load_lds16(pB + (size_t)128 * H_ + (k0_), d_ + 8192);                      \
}

#define TILE_STEP(kt, WAITSTR, DO_STAGE)                                       \
  {                                                                            \
    const short* slot = lds + ((kt) & 3) * SLOT_SH;                            \
    short* nslot = lds + (((kt) + 3) & 3) * SLOT_SH;                           \
    asm volatile(WAITSTR ::: "memory");                                        \
    __builtin_amdgcn_s_barrier();                                              \
    __builtin_amdgcn_sched_barrier(0);                                         \
    short8 a[4], b[4];                                                         \
    _Pragma("unroll")                                                          \
    for (int i = 0; i < 4; ++i)                                                \
      a[i] = *(const short8*)&slot[(wr * 128 + i * 16 + l15) * 32 + pcs];      \
    _Pragma("unroll")                                                          \
    for (int i = 0; i < 4; ++i)                                                \
      b[i] = *(const short8*)&slot[8192 + (wc * 64 + i * 16 + l15) * 32 + pcs];\
    if (DO_STAGE) { STAGE_A(nslot, ((kt) + 3) * 32) }                          \
    asm volatile("s_waitcnt lgkmcnt(0)" ::: "memory");                         \
    __builtin_amdgcn_sched_barrier(0);                                         \
    __builtin_amdgcn_s_setprio(1);                                             \
    mfma16(a, b, acc, 0);                                                      \
    __builtin_amdgcn_s_setprio(0);                                             \
    __builtin_amdgcn_s_barrier();                                              \
    _Pragma("unroll")                                                          \
    for (int i = 0; i < 4; ++i)                                                \
      a[i] = *(const short8*)&slot[(wr * 128 + 64 + i * 16 + l15) * 32 + pcs]; \
    if (DO_STAGE) { STAGE_B(nslot, ((kt) + 3) * 32) }                          \
    asm volatile("s_waitcnt lgkmcnt(0)" ::: "memory");                         \
    __builtin_amdgcn_sched_barrier(0);                                         \
    __builtin_amdgcn_s_setprio(1);                                             \
    mfma16(a, b, acc, 4);                                                      \
    __builtin_amdgcn_s_setprio(0);                                             \
  }

__global__ __launch_bounds__(512, 2) void mfma_gemm(const __hip_bfloat16* __restrict__ Ab,
                                                    const __hip_bfloat16* __restrict__ Wt,
                                                    __hip_bfloat16* __restrict__ XY,
                                                    float* __restrict__ ST,
                                                    float* __restrict__ CC) {
    __shared__ short lds[4 * SLOT_SH];   // 128 KiB
    int tid = threadIdx.x;
    int wave = tid >> 6, lane = tid & 63;
    int wr = wave >> 2, wc = wave & 3;
    int l15 = lane & 15;
    int pcs = ((lane >> 4) ^ ((l15 >> 1) & 3)) * 8;   // swizzled chunk, in shorts

    // bijective XCD swizzle: nwg=732, q=91, r=4 (m204 formula)
    int orig = blockIdx.x;
    int xcd = orig & 7, loc = orig >> 3;
    int wg = (xcd < 4 ? xcd * 92 : 368 + (xcd - 4) * 91) + loc;
    int mt = wg / 12, nt = wg - mt * 12;
    int m0 = mt << 8, n0 = nt << 8;

    const __hip_bfloat16* Bt;
    if (m0 < YB2)        Bt = Wt + (size_t)1 * HS_ * H_;  // X: h_end panel
    else if (m0 < GB)    Bt = Wt + (size_t)2 * HS_ * H_;  // Y: h_mean panel
    else if (m0 < CLSB)  Bt = Wt;                         // ST: h_start panel
    else                 Bt = Wt + (size_t)3 * HS_ * H_;  // CC: cls panel

    // staging addresses: wave w covers rows [w*16, w*16+16) and +128;
    // per-lane logical chunk lc = (lane&3) ^ ((row>>1)&3) = (lane&3)^((lane>>3)&3)
    int srow = wave * 16 + (lane >> 2);
    int lcS = ((lane & 3) ^ ((lane >> 3) & 3)) * 8;       // elements
    const __hip_bfloat16* pA = Ab + (size_t)(m0 + srow) * H_ + lcS;
    const __hip_bfloat16* pB = Bt + (size_t)(n0 + srow) * H_ + lcS;
    int dstoff = wave * 1024;                             // bytes within slot half

    f32x4 acc[8][4] = {};

    // prologue: stage tiles 0,1,2
#pragma unroll
    for (int t = 0; t < 3; ++t) {
        STAGE_A(lds + t * SLOT_SH, t * 32)
        STAGE_B(lds + t * SLOT_SH, t * 32)
    }

    for (int kt = 0; kt < NKT - 3; ++kt)
        TILE_STEP(kt, "s_waitcnt vmcnt(8)", true)
    TILE_STEP(NKT - 3, "s_waitcnt vmcnt(8)", false)
    TILE_STEP(NKT - 2, "s_waitcnt vmcnt(4)", false)
    TILE_STEP(NKT - 1, "s_waitcnt vmcnt(0)", false)

    // C-write. 16x16x32 C/D layout: col(n)=lane&15, row(m)=(lane>>4)*4+reg
    int mb = m0 + wr * 128, nb = n0 + wc * 64;
#pragma unroll
    for (int mf = 0; mf < 8; ++mf) {
#pragma unroll
        for (int nf = 0; nf < 4; ++nf) {
            int n = nb + nf * 16 + l15;
            int mr = mb + mf * 16 + (lane >> 4) * 4;
#pragma unroll
            for (int r = 0; r < 4; ++r) {
                int m = mr + r;
                float v = acc[mf][nf][r];
                if (m < XYROWS) {
                    XY[(size_t)m * HS_ + n] = __float2bfloat16(v);
                } else if (m < CLSB) {
                    ST[(size_t)(m - GB) * HS_ + n] = v;
                } else if (m < CLSB + 16) {
                    CC[(size_t)(m - CLSB) * HS_ + n] = v;
                }
            }
        }
    }
}

// ---------------------------------------------------------------------------
// combine — r10-proven body, fence-free (r11 proved __threadfence poisons
// per-XCD L2 reuse: combine 102 -> 178 us). ONE 512-thread block (8 waves)
// per (b,s); stage Ys / c0=bf16(ST+CC+b1) / w into LDS once; waves take
// pairs pr = wave, wave+8, ... launch_bounds(512,4) -> 2 blocks/CU.
// Per-element math and reduction order identical to r2/r8/r10.
// ---------------------------------------------------------------------------
__global__ __launch_bounds__(512, 4) void combine_kernel(
    const float* __restrict__ ST, const float* __restrict__ CC,
    const float* __restrict__ b1, const float* __restrict__ w_score,
    const __hip_bfloat16* __restrict__ XY,
    const float* __restrict__ b_score, const float* __restrict__ W_type,
    const int* __restrict__ starts, const int* __restrict__ ends,
    float* __restrict__ scores, float* __restrict__ tgold) {
    __shared__ unsigned short ysL[HS_];
    __shared__ unsigned short cvL[HS_];
    __shared__ unsigned short wvL[HS_];
    int x = blockIdx.x;
    int b = x & 15, s = x >> 4;          // XCD = x%8 = b%8
    int bs = b * S_ + s;
    int tid = threadIdx.x;
    int wave = tid >> 6, lane = tid & 63;
    int sv = starts[bs], ev = ends[bs];
    int gi = min(max(ev - sv, 0), L_ - 1);
    int sc = min(max(sv, 0), TX_ - 1);
    float bs0 = b_score[0];

    // stage shared streams into LDS (once per block)
    const unsigned short* Ysr = (const unsigned short*)(XY + (size_t)(YB2 + b * TX_ + sc) * HS_);
    const float* STr = ST + (size_t)bs * HS_;
    const float* CCr = CC + (size_t)b * HS_;
    union U8 { short8 s; unsigned short u[8]; };
    for (int d = tid * 8; d < HS_; d += 512 * 8) {
        *(short8*)&ysL[d] = *(const short8*)(Ysr + d);
        float4 sa = *(const float4*)(STr + d), sb = *(const float4*)(STr + d + 4);
        float4 ca = *(const float4*)(CCr + d), cb = *(const float4*)(CCr + d + 4);
        float4 ba = *(const float4*)(b1 + d),  bb = *(const float4*)(b1 + d + 4);
        U8 uc;
        uc.u[0] = f2bf(sa.x + ca.x + ba.x); uc.u[1] = f2bf(sa.y + ca.y + ba.y);
        uc.u[2] = f2bf(sa.z + ca.z + ba.z); uc.u[3] = f2bf(sa.w + ca.w + ba.w);
        uc.u[4] = f2bf(sb.x + cb.x + bb.x); uc.u[5] = f2bf(sb.y + cb.y + bb.y);
        uc.u[6] = f2bf(sb.z + cb.z + bb.z); uc.u[7] = f2bf(sb.w + cb.w + bb.w);
        *(short8*)&cvL[d] = uc.s;
        float4 wa = *(const float4*)(w_score + d), wb = *(const float4*)(w_score + d + 4);
        U8 uw;
        uw.u[0] = f2bf(wa.x); uw.u[1] = f2bf(wa.y); uw.u[2] = f2bf(wa.z); uw.u[3] = f2bf(wa.w);
        uw.u[4] = f2bf(wb.x); uw.u[5] = f2bf(wb.y); uw.u[6] = f2bf(wb.z); uw.u[7] = f2bf(wb.w);
        *(short8*)&wvL[d] = uw.s;
    }
    __syncthreads();

    for (int pr = wave; pr < L_ / 2; pr += 8) {
        int l0 = pr * 2, l1 = l0 + 1;
        int pc0 = min(max(sv + l0, 0), TX_ - 2);
        int pc1 = min(max(sv + l1, 0), TX_ - 2);
        float inv0 = 1.0f / (float)(l0 + 1);
        float inv1 = 1.0f / (float)(l1 + 1);
        bool isg0 = (l0 == gi), isg1 = (l1 == gi);
        bool anyg = isg0 || isg1;

        const unsigned short* X0 = (const unsigned short*)(XY + (size_t)(b * TX_ + pc0) * HS_);
        const unsigned short* X1 = (const unsigned short*)(XY + (size_t)(b * TX_ + pc1) * HS_);
        const unsigned short* Y0 = (const unsigned short*)(XY + (size_t)(YB2 + b * TX_ + pc0 + 1) * HS_);
        const unsigned short* Y1 = (const unsigned short*)(XY + (size_t)(YB2 + b * TX_ + pc1 + 1) * HS_);

        float local0 = 0.f, local1 = 0.f, t0 = 0.f, t1 = 0.f, t2 = 0.f;
#pragma unroll 2
        for (int j = 0; j < 6; j++) {
            int d = j * 512 + lane * 8;
            short8 xv0 = *(const short8*)(X0 + d);
            short8 xv1 = *(const short8*)(X1 + d);
            short8 yv0 = *(const short8*)(Y0 + d);
            short8 yv1 = *(const short8*)(Y1 + d);
            short8 ys8 = *(const short8*)&ysL[d];
            short8 cv8 = *(const short8*)&cvL[d];
            short8 wv8 = *(const short8*)&wvL[d];
#pragma unroll
            for (int q = 0; q < 8; q++) {
                float ys = bf2f(((const unsigned short*)&ys8)[q]);
                float cvq = bf2f(((const unsigned short*)&cv8)[q]);
                float w  = bf2f(((const unsigned short*)&wv8)[q]);
                float v0 = fmaf(bf2f(((const unsigned short*)&yv0)[q]) - ys, inv0, cvq) +
                           bf2f(((const unsigned short*)&xv0)[q]);
                float v1 = fmaf(bf2f(((const unsigned short*)&yv1)[q]) - ys, inv1, cvq) +
                           bf2f(((const unsigned short*)&xv1)[q]);
                float g0 = gelu_exact(v0);
                float g1 = gelu_exact(v1);
                local0 = fmaf(g0, w, local0);
                local1 = fmaf(g1, w, local1);
                if (anyg) {   // wave-uniform branch
                    float gg = isg0 ? g0 : g1;
                    t0 = fmaf(gg, W_type[(d + q) * NT_ + 0], t0);
                    t1 = fmaf(gg, W_type[(d + q) * NT_ + 1], t1);
                    t2 = fmaf(gg, W_type[(d + q) * NT_ + 2], t2);
                }
            }
        }
#pragma unroll
        for (int off = 32; off >= 1; off >>= 1) {
            local0 += __shfl_down(local0, off);
            local1 += __shfl_down(local1, off);
        }
        if (lane == 0) {
            scores[(size_t)bs * L_ + l0] = local0 + bs0;
            scores[(size_t)bs * L_ + l1] = local1 + bs0;
        }
        if (anyg) {
#pragma unroll
            for (int off = 32; off >= 1; off >>= 1) {
                t0 += __shfl_down(t0, off);
                t1 += __shfl_down(t1, off);
                t2 += __shfl_down(t2, off);
            }
            if (lane == 0) {
                tgold[bs * NT_ + 0] = t0;
                tgold[bs * NT_ + 1] = t1;
                tgold[bs * NT_ + 2] = t2;
            }
        }
    }
}

// ---------------------------------------------------------------------------
// final loss: one block, one thread per (b,s)
// ---------------------------------------------------------------------------
__global__ __launch_bounds__(512) void loss_kernel(
    const float* __restrict__ scores, const float* __restrict__ tgold,
    const int* __restrict__ mask, const int* __restrict__ starts,
    const int* __restrict__ ends, const int* __restrict__ types,
    const float* __restrict__ b_type, float* __restrict__ out) {
    __shared__ int svl[B_];
    __shared__ float r[3][8];
    int tid = threadIdx.x;
    int b = tid / S_;
    if (tid < B_) svl[tid] = 0;
    __syncthreads();
    {
        int part = 0;
        const int* mp = mask + tid * 16;
#pragma unroll
        for (int i = 0; i < 16; i++) part += mp[i];
        atomicAdd(&svl[tid / (T_ / 16)], part);
    }
    __syncthreads();
    int vl = svl[b];
    int lt = max(1, vl - 2);
    int sv = starts[tid], ev = ends[tid];
    int gold = ev - sv;
    bool valid = (sv >= 1) && (sv <= lt) && (ev >= sv) && (ev <= lt) && (gold < L_);
    int emax = min(sv + L_ - 1, lt);
    const float* sp = scores + (size_t)tid * L_;
    float m = -1e30f;
    for (int l = 0; l < L_; l++) {
        float v = (sv + l <= emax) ? sp[l] : -1e9f;
        m = fmaxf(m, v);
    }
    float sum = 0.f;
    for (int l = 0; l < L_; l++) {
        float v = (sv + l <= emax) ? sp[l] : -1e9f;
        sum += expf(v - m);
    }
    int gi = min(max(gold, 0), L_ - 1);
    float vg = (sv + gi <= emax) ? sp[gi] : -1e9f;
    float end_loss = (m + logf(sum)) - vg;

    float t0 = tgold[tid * 3 + 0] + b_type[0];
    float t1 = tgold[tid * 3 + 1] + b_type[1];
    float t2 = tgold[tid * 3 + 2] + b_type[2];
    float tm = fmaxf(t0, fmaxf(t1, t2));
    float tsum = expf(t0 - tm) + expf(t1 - tm) + expf(t2 - tm);
    int tg = min(max(types[tid], 0), NT_ - 1);
    float tv = (tg == 0) ? t0 : ((tg == 1) ? t1 : t2);
    float type_loss = (tm + logf(tsum)) - tv;

    float ve = valid ? end_loss : 0.f;
    float vt = valid ? type_loss : 0.f;
    float vc = valid ? 1.f : 0.f;
    for (int off = 32; off >= 1; off >>= 1) {
        ve += __shfl_down(ve, off);
        vt += __shfl_down(vt, off);
        vc += __shfl_down(vc, off);
    }
    if ((tid & 63) == 0) {
        int w = tid >> 6;
        r[0][w] = ve; r[1][w] = vt; r[2][w] = vc;
    }
    __syncthreads();
    if (tid == 0) {
        float se = 0, st = 0, n = 0;
        for (int w = 0; w < 8; w++) { se += r[0][w]; st += r[1][w]; n += r[2][w]; }
        float denom = fmaxf(n, 1.f);
        out[0] = (n > 0.f) ? (se / denom + st / denom) : 0.f;
    }
}

// ---------------------------------------------------------------------------
extern "C" void kernel_launch(void* const* d_in, const int* in_sizes, int n_in,
                              void* d_out, int out_size, void* d_ws, size_t ws_size,
                              hipStream_t stream) {
    const float* h       = (const float*)d_in[0];
    const int*   mask    = (const int*)d_in[1];
    const int*   starts  = (const int*)d_in[2];
    const int*   ends    = (const int*)d_in[3];
    const int*   types   = (const int*)d_in[4];
    const float* W1      = (const float*)d_in[5];
    const float* b1      = (const float*)d_in[6];
    const float* w_score = (const float*)d_in[7];
    const float* b_score = (const float*)d_in[8];
    const float* W_type  = (const float*)d_in[9];
    const float* b_type  = (const float*)d_in[10];
    float* out = (float*)d_out;

    char* ws = (char*)d_ws;
    size_t off = 0;
    __hip_bfloat16* Ab = (__hip_bfloat16*)(ws + off); off += (size_t)AROWS * H_ * 2;
    __hip_bfloat16* XY = (__hip_bfloat16*)(ws + off); off += (size_t)XYROWS * HS_ * 2;
    __hip_bfloat16* Wt = (__hip_bfloat16*)(ws + off); off += (size_t)4 * HS_ * H_ * 2;
    float* ST     = (float*)(ws + off);               off += (size_t)512 * HS_ * 4;
    float* CC     = (float*)(ws + off);               off += (size_t)16 * HS_ * 4;
    float* scores = (float*)(ws + off);               off += (size_t)B_ * S_ * L_ * 4;
    float* tgold  = (float*)(ws + off);               off += (size_t)B_ * S_ * NT_ * 4;
    float4* partial = (float4*)XY;  // aliases XY; consumed by pass3 before GEMM writes XY

    hipLaunchKernelGGL(prep_kernel, dim3(P1_BLOCKS + 48 * 48), dim3(256), 0, stream,
                       (const float4*)h, partial, W1, Wt);
    hipLaunchKernelGGL(cumsum_pass3, dim3(P1_BLOCKS + B_ * S_ + B_), dim3(256),
                       0, stream, (const float4*)h, (const float4*)partial, (ushort4*)Ab,
                       h, starts);
    hipLaunchKernelGGL(mfma_gemm, dim3((AROWS / 256) * 12), dim3(512), 0, stream,
                       Ab, Wt, XY, ST, CC);
    hipLaunchKernelGGL(combine_kernel, dim3(B_ * S_), dim3(512), 0, stream,
                       ST, CC, b1, w_score, XY, b_score, W_type, starts, ends,
                       scores, tgold);
    hipLaunchKernelGGL(loss_kernel, dim3(1), dim3(512), 0, stream,
                       scores, tgold, mask, starts, ends, types, b_type, out);
}